// Round 1
// baseline (308.079 us; speedup 1.0000x reference)
//
#include <hip/hip_runtime.h>

// Advect: minmod-limited flux stencil along last axis.
// L = 8192 (ghost-padded), OUT = L-4 = 8188 per row, rows = B*M = 4096.
//
// main[k] = net[k] - net[k+1]
// net[j]  = fm(j) + fp(j)
//   fm(j) = (v[j+2] >= 0 || j == L-4) ? 0 : F[j+2] - hs[j+1]
//   fp(j) = (v[j+1] <= 0 || j == 0)   ? 0 : F[j+1] + hs[j]
//   hs(i) = 0.5 * minmod3( th*(F[i+1]-F[i]), 0.5*(F[i+2]-F[i]), th*(F[i+2]-F[i+1]) )
//   F[i]  = rho[i] * v[i]

#define TH 2.0f

__device__ __forceinline__ float minmod3(float a, float b, float c) {
    float mn = fminf(fminf(a, b), c);
    float mx = fmaxf(fmaxf(a, b), c);
    return (mn < 0.0f) ? fminf(mx, 0.0f) : mn;
}

__global__ __launch_bounds__(256) void advect_kernel(
    const float* __restrict__ rho, const float* __restrict__ v,
    float* __restrict__ out, int L, int OUT, int GPR)
{
    int g = blockIdx.x * blockDim.x + threadIdx.x;   // group of 4 outputs
    if (g >= GPR) return;
    long row = blockIdx.y;
    const float* r  = rho + row * L;
    const float* vp = v   + row * L;
    int k0 = g * 4;

    // 8-wide halo load: outputs k0..k0+3 need indices k0..k0+7 (both float4-aligned)
    float4 ra = *(const float4*)(r  + k0);
    float4 rb = *(const float4*)(r  + k0 + 4);
    float4 va = *(const float4*)(vp + k0);
    float4 vb = *(const float4*)(vp + k0 + 4);

    float V[8] = {va.x, va.y, va.z, va.w, vb.x, vb.y, vb.z, vb.w};
    float R[8] = {ra.x, ra.y, ra.z, ra.w, rb.x, rb.y, rb.z, rb.w};
    float F[8];
#pragma unroll
    for (int i = 0; i < 8; ++i) F[i] = R[i] * V[i];

    // half-slope hs[i] ~ global index k0+i, i in [0,5]
    float hs[6];
#pragma unroll
    for (int i = 0; i < 6; ++i) {
        float c0 = TH   * (F[i+1] - F[i]);
        float c1 = 0.5f * (F[i+2] - F[i]);
        float c2 = TH   * (F[i+2] - F[i+1]);
        hs[i] = 0.5f * minmod3(c0, c1, c2);
    }

    // net[j] ~ global index k0+j, j in [0,4]
    float net[5];
#pragma unroll
    for (int j = 0; j < 5; ++j) {
        int gj = k0 + j;
        float fm = (V[j+2] >= 0.0f || gj == OUT) ? 0.0f : (F[j+2] - hs[j+1]);
        float fp = (V[j+1] <= 0.0f || gj == 0)   ? 0.0f : (F[j+1] + hs[j]);
        net[j] = fm + fp;
    }

    float4 o;
    o.x = net[0] - net[1];
    o.y = net[1] - net[2];
    o.z = net[2] - net[3];
    o.w = net[3] - net[4];
    *(float4*)(out + row * OUT + k0) = o;
}

extern "C" void kernel_launch(void* const* d_in, const int* in_sizes, int n_in,
                              void* d_out, int out_size, void* d_ws, size_t ws_size,
                              hipStream_t stream) {
    const float* rho = (const float*)d_in[0];
    const float* v   = (const float*)d_in[1];
    float* out = (float*)d_out;

    const int L    = 8192;
    const int rows = in_sizes[0] / L;   // B*M = 4096
    const int OUT  = L - 4;             // 8188
    const int GPR  = OUT / 4;           // 2047 float4 groups per row

    dim3 block(256);
    dim3 grid((GPR + 255) / 256, rows); // (8, 4096)
    hipLaunchKernelGGL(advect_kernel, grid, block, 0, stream,
                       rho, v, out, L, OUT, GPR);
}